// Round 17
// baseline (94.042 us; speedup 1.0000x reference)
//
#include <hip/hip_runtime.h>
#include <stdint.h>

#define KK 5
#define TT 512

// ---- cross-lane helpers (8-lane groups; 8 | 32 so groups never straddle the
// ds_swizzle 32-lane boundary) ----
template<int P> __device__ __forceinline__ float swzf(float v) {
  return __int_as_float(__builtin_amdgcn_ds_swizzle(__float_as_int(v), P));
}
template<int P> __device__ __forceinline__ int swzi(int v) {
  return __builtin_amdgcn_ds_swizzle(v, P);
}
// broadcast lane (group*8 + i): offset = (i<<5) | 0x18
#define BC0 0x018
#define BC1 0x038
#define BC2 0x058
#define BC3 0x078
#define BC4 0x098
// xor-butterfly within 8-lane group: offset = (m<<10) | 0x1F
#define X1 0x041F
#define X2 0x081F
#define X4 0x101F

__device__ __forceinline__ float sel5f(float v0,float v1,float v2,float v3,float v4,int ct){
  float u=v0; u=(ct==1)?v1:u; u=(ct==2)?v2:u; u=(ct==3)?v3:u; u=(ct==4)?v4:u; return u;
}
__device__ __forceinline__ uint32_t sel5u(uint32_t w0,uint32_t w1,uint32_t w2,uint32_t w3,uint32_t w4,int ct){
  uint32_t u=w0; u=(ct==1)?w1:u; u=(ct==2)?w2:u; u=(ct==3)?w3:u; u=(ct==4)?w4:u; return u;
}
__device__ __forceinline__ int telt(const int4 (&tp)[2], int s) {   // s compile-time
  const int4 v = (s < 4) ? tp[0] : tp[1];
  const int m = s & 3;
  return m == 0 ? v.x : (m == 1 ? v.y : (m == 2 ? v.z : v.w));
}

// load one 8-step column block: element t for t = 8k+1 .. 8k+8 (clamped)
__device__ __forceinline__ void loadCol(float (&d)[8], const float* __restrict__ colp, int k) {
  const int t0 = k * 8 + 1;
  if (k < TT / 8 - 1) {
#pragma unroll
    for (int s = 0; s < 8; ++s) d[s] = colp[(t0 + s) * KK];
  } else {
#pragma unroll
    for (int s = 0; s < 8; ++s) d[s] = colp[min(t0 + s, TT - 1) * KK];
  }
}
// aligned tag window [8k, 8k+7]
__device__ __forceinline__ void loadTag(int4 (&tp)[2], const int* __restrict__ tg, int k) {
  tp[0] = *(const int4*)(tg + 8 * k);
  tp[1] = *(const int4*)(tg + 8 * k + 4);
}

// ---------------- Viterbi: 8 scan steps; raw bp word -> GLOBAL (coalesced) ----
__device__ __forceinline__ void vit_blk(const float (&pv)[8], int k, int len_eff,
                                        const float (&trc)[KK], float& a,
                                        int jj, int g, int r,
                                        uint32_t* bw) {
  uint32_t bits = 0;
#pragma unroll
  for (int s = 0; s < 8; ++s) {
    const float av0 = swzf<BC0>(a), av1 = swzf<BC1>(a), av2 = swzf<BC2>(a),
                av3 = swzf<BC3>(a), av4 = swzf<BC4>(a);
    const float s0 = av0 + trc[0], s1 = av1 + trc[1], s2 = av2 + trc[2],
                s3 = av3 + trc[3], s4 = av4 + trc[4];
    const float bm = fmaxf(fmaxf(fmaxf(s0, s1), fmaxf(s2, s3)), s4);
    int bi = 4;                      // first-max tie-break == jnp.argmax
    bi = (s3 == bm) ? 3 : bi;
    bi = (s2 == bm) ? 2 : bi;
    bi = (s1 == bm) ? 1 : bi;
    bi = (s0 == bm) ? 0 : bi;
    const int t = k * 8 + s + 1;
    const bool act = (t < len_eff);
    a = act ? (bm + pv[s]) : a;
    const int bie = act ? bi : jj;   // identity backpointer when frozen
    bits |= (uint32_t)bie << (3 * s);
  }
  // lanes r<5 write 40 consecutive dwords across the wave: coalesced
  if (r < 5) bw[k * 40 + g * 5 + jj] = bits;
}

// ---------------- forward: 8 linear-space steps + fused score + renorm -----
__device__ __forceinline__ void fwd_blk(const float (&pv)[8], const int4 (&tp)[2],
                                        int k, int len, int len_eff,
                                        const float (&Wc)[KK], const float (&trcR)[KK],
                                        float& p, float& Cacc,
                                        float& pvcar, int& tagcar,
                                        float& usum, float& bsum, int r) {
#pragma unroll
  for (int s = 0; s < 8; ++s) {
    const float p0 = swzf<BC0>(p), p1 = swzf<BC1>(p), p2 = swzf<BC2>(p),
                p3 = swzf<BC3>(p), p4 = swzf<BC4>(p);
    const float u  = fmaf(p1, Wc[1], p0 * Wc[0]);
    const float v2 = fmaf(p3, Wc[3], p2 * Wc[2]);
    const float acc = fmaf(p4, Wc[4], u + v2);
    const float E = __expf(pv[s]);
    const int t = k * 8 + s + 1;
    const bool act = (t < len_eff);
    p = act ? (acc * E) : p;
  }
  // fused score over window t in [8k, 8k+7] (off the p chain)
#pragma unroll
  for (int s2 = 0; s2 < 8; ++s2) {
    const int t = k * 8 + s2;
    const int ct = telt(tp, s2);
    const int pt = (s2 == 0) ? tagcar : telt(tp, s2 - 1);
    const float potv = (s2 == 0) ? pvcar : pv[s2 - 1];
    const bool um = (t < len) && (ct == r);        // lanes 5..7 never match
    usum += um ? potv : 0.0f;
    bsum += (um && t >= 1) ? sel5f(trcR[0], trcR[1], trcR[2], trcR[3], trcR[4], pt) : 0.0f;
  }
  pvcar = pv[7];          // pot[8(k+1)][jj]
  tagcar = telt(tp, 7);   // tag[8k+7]
  // renorm once per block
  float m = p;
  m = fmaxf(m, swzf<X1>(m));
  m = fmaxf(m, swzf<X2>(m));
  m = fmaxf(m, swzf<X4>(m));           // lanes r>=5 hold p=0: never the max
  p *= (1.0f / m);
  Cacc += __logf(m);
}

// ---------------------------------------------------------------------------
// grid: 2*(B/8) blocks x 64 threads (1 wave). 8 batches/wave, 8 lanes/batch
// (5 compute tags). role via (blockIdx>>3)&1; blocks u and u+8 share batches
// and XCD. No barriers. bp words live in GLOBAL scratch (frees LDS: only the
// 2.1 KB s_chosen remains -> 3-5x more resident waves hide the swizzle chain).
// ---------------------------------------------------------------------------
__launch_bounds__(64)
__global__ void crf_kernel(const float* __restrict__ pot,
                           const float* __restrict__ trans,
                           const int* __restrict__ lens,
                           const int* __restrict__ tags,
                           uint32_t* bwords,
                           float* __restrict__ out,
                           int B, int T) {
  __shared__ uint32_t s_chosen[8 * 65];
  const int lane = threadIdx.x;
  const int g = lane >> 3, r = lane & 7;
  const int jj = (r < 5) ? r : 4;
  const unsigned u = blockIdx.x;
  const int role = (u >> 3) & 1;
  const int idx = (int)((u & 7u) | ((u >> 4) << 3));
  const int b = idx * 8 + g;
  const int len = lens[b];
  const int len_eff = (r < 5) ? len : 0;
  const float* __restrict__ prow = pot + (size_t)b * (T * KK);
  const float* __restrict__ colp = prow + jj;

  int ml = len;
  ml = max(ml, __shfl_xor(ml, 8));
  ml = max(ml, __shfl_xor(ml, 16));
  ml = max(ml, __shfl_xor(ml, 32));
  const int nblk = (ml + 7) >> 3;       // wave-uniform

  if (role == 0) {
    // ========================= Viterbi =========================
    uint32_t* bw = bwords + (size_t)idx * (TT / 8) * 40;   // this group's arena
    float trc[KK];
#pragma unroll
    for (int i = 0; i < KK; ++i) trc[i] = trans[i * KK + jj];
    float a = (r < 5) ? prow[jj] : -3.0e38f;

    float pA[8], pB[8], pC[8];
    loadCol(pA, colp, 0);
    loadCol(pB, colp, min(1, nblk - 1));
    loadCol(pC, colp, min(2, nblk - 1));
    int blk = 0;
    while (true) {
      vit_blk(pA, blk, len_eff, trc, a, jj, g, r, bw);
      if (++blk == nblk) break;
      loadCol(pA, colp, min(blk + 2, nblk - 1));
      vit_blk(pB, blk, len_eff, trc, a, jj, g, r, bw);
      if (++blk == nblk) break;
      loadCol(pB, colp, min(blk + 2, nblk - 1));
      vit_blk(pC, blk, len_eff, trc, a, jj, g, r, bw);
      if (++blk == nblk) break;
      loadCol(pC, colp, min(blk + 2, nblk - 1));
    }
    // final argmax (first-max) over lanes r<5 of each group
    float bm = a;
    bm = fmaxf(bm, swzf<X1>(bm));
    bm = fmaxf(bm, swzf<X2>(bm));
    bm = fmaxf(bm, swzf<X4>(bm));
    int cand = (r < 5 && a == bm) ? r : 7;
    cand = min(cand, swzi<X1>(cand));
    cand = min(cand, swzi<X2>(cand));
    cand = min(cand, swzi<X4>(cand));
    const int last = cand;

    // ====== post-scan backtrace: raw-bits walk (lane r==0 per group) ======
    // Identity backpointers beyond len-1: no length checks needed in the walk.
    // Loads are tag-independent -> 2-deep prefetch hides L2 latency; tails
    // overlap across the many resident waves.
    if (r == 0) {
      int tag = last;
      int k2 = nblk - 1;
      uint32_t A0, A1, A2, A3, A4, B0, B1, B2, B3, B4;
      {
        const uint32_t* pw = bw + k2 * 40 + g * 5;
        A0 = pw[0]; A1 = pw[1]; A2 = pw[2]; A3 = pw[3]; A4 = pw[4];
      }
      {
        const int kb = max(k2 - 1, 0);
        const uint32_t* pw = bw + kb * 40 + g * 5;
        B0 = pw[0]; B1 = pw[1]; B2 = pw[2]; B3 = pw[3]; B4 = pw[4];
      }
      for (; k2 >= 0; --k2) {
        // prefetch block k2-2 while walking k2
        const int kc = max(k2 - 2, 0);
        const uint32_t* pw = bw + kc * 40 + g * 5;
        const uint32_t C0 = pw[0], C1 = pw[1], C2 = pw[2], C3 = pw[3], C4 = pw[4];
        uint32_t dec = 0;
#pragma unroll
        for (int s = 7; s >= 0; --s) {
          const uint32_t w = sel5u(A0, A1, A2, A3, A4, tag);
          const int prev = (int)((w >> (3 * s)) & 7u);   // tag at position k2*8+s
          dec |= (uint32_t)prev << (3 * s);
          tag = prev;
        }
        s_chosen[g * 65 + k2] = dec;
        A0 = B0; A1 = B1; A2 = B2; A3 = B3; A4 = B4;
        B0 = C0; B1 = C1; B2 = C2; B3 = C3; B4 = C4;
      }
    }

    // ============ coalesced decoded write (all lanes) ============
    float* __restrict__ orow = out + (size_t)b * T;
#pragma unroll
    for (int kk = 0; kk < 8; ++kk) {
      const int k2 = kk * 8 + r;
      const uint32_t w = s_chosen[g * 65 + k2];
      const int base = k2 * 8;
      float f[8];
#pragma unroll
      for (int pI = 0; pI < 8; ++pI)
        f[pI] = (base + pI < len) ? (float)((w >> (3 * pI)) & 7u) : 0.0f;
      *(float4*)(orow + base)     = make_float4(f[0], f[1], f[2], f[3]);
      *(float4*)(orow + base + 4) = make_float4(f[4], f[5], f[6], f[7]);
    }

  } else {
    // ==================== forward + fused score ====================
    float Wc[KK], trcR[KK];
#pragma unroll
    for (int i = 0; i < KK; ++i) {
      trcR[i] = trans[i * KK + jj];
      Wc[i] = __expf(trcR[i]);
    }
    const float pj0 = prow[jj];
    float p = (r < 5) ? __expf(pj0) : 0.0f;
    float Cacc = 0.0f;
    float usum = 0.0f, bsum = 0.0f;
    float pvcar = pj0;                   // pot[0][jj]
    int tagcar = 0;                      // unused at t=0 (binary starts t=1)
    const int* __restrict__ tg = tags + (size_t)b * T;

    float pA[8], pB[8], pC[8];
    int4 TA[2], TB[2], TC[2];
    loadCol(pA, colp, 0);                loadTag(TA, tg, 0);
    loadCol(pB, colp, min(1, nblk - 1)); loadTag(TB, tg, min(1, nblk - 1));
    loadCol(pC, colp, min(2, nblk - 1)); loadTag(TC, tg, min(2, nblk - 1));
    int blk = 0;
    while (true) {
      fwd_blk(pA, TA, blk, len, len_eff, Wc, trcR, p, Cacc, pvcar, tagcar, usum, bsum, r);
      if (++blk == nblk) break;
      loadCol(pA, colp, min(blk + 2, nblk - 1)); loadTag(TA, tg, min(blk + 2, nblk - 1));
      fwd_blk(pB, TB, blk, len, len_eff, Wc, trcR, p, Cacc, pvcar, tagcar, usum, bsum, r);
      if (++blk == nblk) break;
      loadCol(pB, colp, min(blk + 2, nblk - 1)); loadTag(TB, tg, min(blk + 2, nblk - 1));
      fwd_blk(pC, TC, blk, len, len_eff, Wc, trcR, p, Cacc, pvcar, tagcar, usum, bsum, r);
      if (++blk == nblk) break;
      loadCol(pC, colp, min(blk + 2, nblk - 1)); loadTag(TC, tg, min(blk + 2, nblk - 1));
    }
    // group totals
    float sc = usum + bsum;
    sc += swzf<X1>(sc);
    sc += swzf<X2>(sc);
    sc += swzf<X4>(sc);
    float ps = p;
    ps += swzf<X1>(ps);
    ps += swzf<X2>(ps);
    ps += swzf<X4>(ps);                  // lanes r>=5 contribute 0
    const float logZ = Cacc + __logf(ps);
    if (r == 0) out[(size_t)B * T + b] = sc - logZ;
  }
}

// ---------------------------------------------------------------------------
extern "C" void kernel_launch(void* const* d_in, const int* in_sizes, int n_in,
                              void* d_out, int out_size, void* d_ws, size_t ws_size,
                              hipStream_t stream) {
  const float* pot   = (const float*)d_in[0];
  const float* trans = (const float*)d_in[1];
  const int*   lens  = (const int*)d_in[2];
  const int*   tags  = (const int*)d_in[3];
  float* out = (float*)d_out;

  const int B = in_sizes[2];
  const int T = in_sizes[3] / B;   // 512

  uint32_t* bwords = (uint32_t*)d_ws;  // (B/8) * 64 blocks * 40 words = 10.5 MB

  const int nblocks = 2 * (B / 8);  // 2048
  crf_kernel<<<nblocks, 64, 0, stream>>>(pot, trans, lens, tags, bwords, out, B, T);
}